// Round 8
// baseline (1251.203 us; speedup 1.0000x reference)
//
#include <hip/hip_runtime.h>
#include <stdint.h>

typedef unsigned long long u64;

static __device__ __forceinline__ int uread(int v) { return __builtin_amdgcn_readfirstlane(v); }
// force fp32 materialization (blocks fma-contraction / reassociation across steps)
static __device__ __forceinline__ float fr(float x) { __asm__ volatile("" : "+v"(x)); return x; }

// bn sign with numpy-faithful fp32 elementwise rounding (bit-frozen since R7 pass):
static __device__ __forceinline__ bool bn_neg(float x, float g, float b, float m, float v) {
    float inv = fr(1.0f / fr(sqrtf(fr(v + 1e-5f))));
    float si  = fr(g * inv);
    float t1  = fr(x - m);
    float t2  = fr(t1 * si);
    float bn  = fr(t2 + b);
    return bn < 0.0f;
}

// ---------------- weight pack kernels (sign: x>=0 -> +1; bit=1 means -1) ----------------

__global__ __launch_bounds__(256) void packw1_kernel(const float* __restrict__ w, float* __restrict__ ws) {
    int id = blockIdx.x * 256 + threadIdx.x;
    if (id >= 27 * 128) return;
    int co = id & 127, j = id >> 7;
    ws[j * 128 + co] = (w[co * 27 + j] < 0.f) ? -1.f : 1.f;
}

__global__ __launch_bounds__(256) void packw_conv_kernel(const float* __restrict__ w, u64* __restrict__ wb,
                                                         int CINW, int COUT) {
    int id = blockIdx.x * 256 + threadIdx.x;
    int total = 9 * CINW * COUT;
    if (id >= total) return;
    int co = id % COUT;
    int rest = id / COUT;
    int wrd = rest % CINW;
    int tap = rest / CINW;
    int CIN = CINW * 64;
    u64 bits = 0;
    const float* p = w + (size_t)(co * CIN + wrd * 64) * 9 + tap;
    for (int b = 0; b < 64; ++b)
        if (p[b * 9] < 0.f) bits |= (1ull << b);
    wb[(size_t)(tap * CINW + wrd) * COUT + co] = bits;
}

// w7 (1024,8192): wave per (o,cw); lane=c_local reads its 16 contiguous pixels (coalesced 4KB/wave)
// bit b of wb[(pixel*8+cw)*1024+o] = sign(w[o*8192 + (cw*64+b)*16 + pixel])
__global__ __launch_bounds__(256) void packw7_kernel(const float* __restrict__ w, u64* __restrict__ wb) {
    int wv = blockIdx.x * 4 + (threadIdx.x >> 6);
    if (wv >= 1024 * 8) return;
    int lane = threadIdx.x & 63;
    int cw = wv & 7, o = wv >> 3;
    const float* p = w + (size_t)o * 8192 + (size_t)(cw * 64 + lane) * 16;
    float f[16];
#pragma unroll
    for (int i = 0; i < 16; i += 4) {
        float4 q = *(const float4*)(p + i);
        f[i] = q.x; f[i + 1] = q.y; f[i + 2] = q.z; f[i + 3] = q.w;
    }
#pragma unroll
    for (int pixel = 0; pixel < 16; ++pixel) {
        u64 bits = __ballot(f[pixel] < 0.f);
        if (lane == 0) wb[(size_t)(pixel * 8 + cw) * 1024 + o] = bits;
    }
}

__global__ __launch_bounds__(256) void packw8_kernel(const float* __restrict__ w, u64* __restrict__ wb) {
    int id = blockIdx.x * 256 + threadIdx.x;
    if (id >= 1024 * 16) return;
    int k = id & 15, o = id >> 4;
    u64 bits = 0;
    const float* p = w + (size_t)o * 1024 + k * 64;
    for (int b = 0; b < 64; ++b)
        if (p[b] < 0.f) bits |= (1ull << b);
    wb[(size_t)k * 1024 + o] = bits;
}

__global__ __launch_bounds__(256) void packw9_kernel(const float* __restrict__ w, u64* __restrict__ wb) {
    int id = blockIdx.x * 256 + threadIdx.x;
    if (id >= 160) return;
    int k = id & 15, o = id >> 4;
    u64 bits = 0;
    const float* p = w + (size_t)o * 1024 + k * 64;
    for (int b = 0; b < 64; ++b)
        if (p[b] < 0.f) bits |= (1ull << b);
    wb[k * 16 + o] = bits;
}

// ---------------- conv1: fp32, Eigen/XLA-CPU accumulation order (BIT-FROZEN, R7 pass) ----------------
__global__ __launch_bounds__(256) void conv1_kernel(
    const float* __restrict__ x, const float* __restrict__ w1s,
    const float* __restrict__ g, const float* __restrict__ bb,
    const float* __restrict__ m, const float* __restrict__ v,
    u64* __restrict__ out, int N)
{
    int lane = threadIdx.x & 63;
    int rid = uread(blockIdx.x * 4 + (threadIdx.x >> 6));
    if (rid >= N * 32) return;
    int n = rid >> 5, y = rid & 31;
    const float* xb = x + (size_t)n * 3072;
    for (int half = 0; half < 2; ++half) {
        int co = half * 64 + lane;
        float w[27];
#pragma unroll
        for (int j = 0; j < 27; ++j) w[j] = w1s[j * 128 + co];
        float gc = g[co], bc = bb[co], mc = m[co], vc = v[co];
        for (int xx = 0; xx < 32; ++xx) {
            float acc = 0.f;
            // strict (ky, kx, ci) order — ci innermost — serial fmaf chain
            for (int ky = 0; ky < 3; ++ky) {
                int yy = y + ky - 1;
                if (yy < 0 || yy >= 32) continue;
                for (int kx = 0; kx < 3; ++kx) {
                    int xs = xx + kx - 1;
                    if (xs < 0 || xs >= 32) continue;
                    for (int ci = 0; ci < 3; ++ci)
                        acc = fmaf(w[ci * 9 + ky * 3 + kx], xb[ci * 1024 + yy * 32 + xs], acc);
                }
            }
            u64 bits = __ballot(bn_neg(acc, gc, bc, mc, vc));
            if (lane == 0) out[(((size_t)n * 32 + y) * 32 + xx) * 2 + half] = bits;
        }
    }
}

// ---------------- binary conv (XNOR-popcount), blocked: XB outputs/wave, vector loads ----------------
// a: [n][H][W][WORDS] bits; wb: [tap*WORDS+w][COW*64]; out: [n][OH][OW][COW] bits
// No readfirstlane: addresses stay in VGPR domain -> deeply batched VMEM loads, no SGPR bottleneck.
template<int WORDS, int COW, bool POOL, bool HAS_BIAS, int H, int W, int XB>
__global__ __launch_bounds__(256) void binconv_kernel(
    const u64* __restrict__ a, const u64* __restrict__ wb,
    const float* __restrict__ g, const float* __restrict__ bb,
    const float* __restrict__ m, const float* __restrict__ v,
    const float* __restrict__ bias, u64* __restrict__ out, int N)
{
    const int OH = POOL ? H / 2 : H, OW = POOL ? W / 2 : W;
    const int COUT = COW * 64;
    const int SP = POOL ? 4 : 1;
    const int OWG = OW / XB;
    int lane = threadIdx.x & 63;
    int wid = blockIdx.x * 4 + (threadIdx.x >> 6);
    if (wid >= N * OH * OWG * COW) return;
    int cw = wid % COW; int tmp = wid / COW;
    int xog = tmp % OWG; tmp /= OWG;
    int yo = tmp % OH; int n = tmp / OH;
    int co = cw * 64 + lane;

    // preload weights once per wave (reused XB*SP times)
    u64 wgt[9 * WORDS];
#pragma unroll
    for (int t = 0; t < 9 * WORDS; ++t)
        wgt[t] = wb[(size_t)t * COUT + co];

    int best[XB];
#pragma unroll
    for (int xb = 0; xb < XB; ++xb) {
        int xo = xog * XB + xb;
        int bestv = 0;
#pragma unroll
        for (int sp = 0; sp < SP; ++sp) {
            int y = POOL ? yo * 2 + (sp >> 1) : yo;
            int x = POOL ? xo * 2 + (sp & 1) : xo;
            int acc = 0, nb = 0;
#pragma unroll
            for (int ky = 0; ky < 3; ++ky) {
                int yy = y + ky - 1;
                if (yy < 0 || yy >= H) continue;
#pragma unroll
                for (int kx = 0; kx < 3; ++kx) {
                    int xx = x + kx - 1;
                    if (xx < 0 || xx >= W) continue;
                    const u64* ap = a + (size_t)((n * H + yy) * W + xx) * WORDS;
#pragma unroll
                    for (int w = 0; w < WORDS; ++w)
                        acc += __popcll(ap[w] ^ wgt[(ky * 3 + kx) * WORDS + w]);
                    nb += WORDS * 64;
                }
            }
            int dot = nb - 2 * acc;   // exact integer == golden's fp32 conv value
            bestv = (sp == 0) ? dot : max(bestv, dot);
        }
        best[xb] = bestv;
    }
    // fl monotone => max commutes with the (dot+bias) rounding; bias constant per channel.
#pragma unroll
    for (int xb = 0; xb < XB; ++xb) {
        int xo = xog * XB + xb;
        float t = (float)best[xb];
        if (HAS_BIAS) t = fr(t + bias[co]);
        u64 bits = __ballot(bn_neg(t, g[co], bb[co], m[co], v[co]));
        if (lane == 0) out[(size_t)((n * OH + yo) * OW + xo) * COW + cw] = bits;
    }
}

// ---------------- binary FC, fp32 bit-exact epilogue (frozen) ----------------
template<int KW, int OWRD>
__global__ __launch_bounds__(256) void binfc_kernel(
    const u64* __restrict__ a, const u64* __restrict__ wb,
    const float* __restrict__ g, const float* __restrict__ bb,
    const float* __restrict__ m, const float* __restrict__ v,
    u64* __restrict__ out, int N)
{
    int lane = threadIdx.x & 63;
    int wid = uread(blockIdx.x * 4 + (threadIdx.x >> 6));
    if (wid >= N * OWRD) return;
    int ow = wid & (OWRD - 1), n = wid / OWRD;
    int o = ow * 64 + lane;
    const u64* ap = a + (size_t)n * KW;
    int acc = 0;
#pragma unroll 8
    for (int k = 0; k < KW; ++k)
        acc += __popcll(ap[k] ^ wb[(size_t)k * (OWRD * 64) + o]);
    float dotf = (float)(KW * 64 - 2 * acc);
    u64 bits = __ballot(bn_neg(dotf, g[o], bb[o], m[o], v[o]));
    if (lane == 0) out[(size_t)n * OWRD + ow] = bits;
}

// ---------------- fc9 + bn(affine=False) + log_softmax, fp32 output (frozen) ----------------
__global__ __launch_bounds__(64) void fc9_kernel(
    const u64* __restrict__ a, const u64* __restrict__ wb,
    const float* __restrict__ m, const float* __restrict__ v, float* __restrict__ out)
{
    int n = blockIdx.x, t = threadIdx.x;
    const u64* ap = a + (size_t)n * 16;
    float val = -1e30f;
    if (t < 10) {
        int acc = 0;
#pragma unroll
        for (int k = 0; k < 16; ++k) acc += __popcll(ap[k] ^ wb[k * 16 + t]);
        float dotf = (float)(1024 - 2 * acc);
        float inv = fr(1.0f / fr(sqrtf(fr(v[t] + 1e-5f))));
        float t1  = fr(dotf - m[t]);
        val = fr(t1 * inv);
    }
    float mx = val;
#pragma unroll
    for (int off = 32; off; off >>= 1) mx = fmaxf(mx, __shfl_xor(mx, off));
    float sh = fr(val - mx);
    double e = (t < 10) ? exp((double)sh) : 0.0;
    double sum = e;
#pragma unroll
    for (int off = 32; off; off >>= 1) sum += __shfl_xor(sum, off);
    if (t < 10) out[n * 10 + t] = (float)((double)sh - log(sum));
}

extern "C" void kernel_launch(void* const* d_in, const int* in_sizes, int n_in,
                              void* d_out, int out_size, void* d_ws, size_t ws_size,
                              hipStream_t stream) {
    // setup_inputs() dict order
    auto F = [&](int i) { return (const float*)d_in[i]; };
    const float* x  = F(0);
    const float* w1 = F(1);  const float* g1 = F(2);  const float* b1 = F(3);
    const float* m1 = F(4);  const float* v1 = F(5);
    const float* w2 = F(6);  const float* g2 = F(7);  const float* b2 = F(8);
    const float* m2 = F(9);  const float* v2 = F(10);
    const float* w3 = F(11); const float* g3 = F(12); const float* b3 = F(13);
    const float* m3 = F(14); const float* v3 = F(15);
    const float* w4 = F(16); const float* g4 = F(17); const float* b4 = F(18);
    const float* m4 = F(19); const float* v4 = F(20);
    const float* w5 = F(21); const float* g5 = F(22); const float* b5 = F(23);
    const float* m5 = F(24); const float* v5 = F(25);
    const float* w6 = F(26); const float* g6 = F(27); const float* b6 = F(28);
    const float* m6 = F(29); const float* v6 = F(30);
    const float* bias2 = F(31);
    const float* w7 = F(32); const float* m7 = F(33); const float* v7 = F(34);
    const float* g7 = F(35); const float* b7 = F(36);
    const float* w8 = F(37); const float* m8 = F(38); const float* v8 = F(39);
    const float* g8 = F(40); const float* b8 = F(41);
    const float* w9 = F(42); const float* m9 = F(43); const float* v9 = F(44);
    (void)in_sizes; (void)n_in; (void)ws_size;

    const int N = out_size / 10;
    u64* ws = (u64*)d_ws;
    size_t off = 0;
    auto carve = [&](size_t nwords) { u64* p = ws + off; off += nwords; return p; };
    float* w1s = (float*)carve(1728);
    u64* w2p = carve(2304);
    u64* w3p = carve(4608);
    u64* w4p = carve(9216);
    u64* w5p = carve(18432);
    u64* w6p = carve(36864);
    u64* w7p = carve(131072);
    u64* w8p = carve(16384);
    u64* w9p = carve(256);
    u64* a1 = carve((size_t)N * 32 * 32 * 2);
    u64* a2 = carve((size_t)N * 16 * 16 * 2);
    u64* a3 = carve((size_t)N * 16 * 16 * 4);
    u64* a4 = carve((size_t)N * 8 * 8 * 4);
    u64* a5 = carve((size_t)N * 8 * 8 * 8);
    u64* a6 = carve((size_t)N * 16 * 8);
    u64* f7 = carve((size_t)N * 16);
    u64* f8 = carve((size_t)N * 16);

    packw1_kernel<<<(3456 + 255) / 256, 256, 0, stream>>>(w1, w1s);
    packw_conv_kernel<<<(2304 + 255) / 256, 256, 0, stream>>>(w2, w2p, 2, 128);
    packw_conv_kernel<<<(4608 + 255) / 256, 256, 0, stream>>>(w3, w3p, 2, 256);
    packw_conv_kernel<<<(9216 + 255) / 256, 256, 0, stream>>>(w4, w4p, 4, 256);
    packw_conv_kernel<<<(18432 + 255) / 256, 256, 0, stream>>>(w5, w5p, 4, 512);
    packw_conv_kernel<<<(36864 + 255) / 256, 256, 0, stream>>>(w6, w6p, 8, 512);
    packw7_kernel<<<(8192 + 3) / 4, 256, 0, stream>>>(w7, w7p);
    packw8_kernel<<<(16384 + 255) / 256, 256, 0, stream>>>(w8, w8p);
    packw9_kernel<<<1, 256, 0, stream>>>(w9, w9p);

    conv1_kernel<<<(N * 32 + 3) / 4, 256, 0, stream>>>(x, w1s, g1, b1, m1, v1, a1, N);

    // binconv: waves = N*OH*(OW/XB)*COW, 4 waves/block
    {   // conv2: pooled, XB=2  -> waves 256*16*8*2
        int wv = N * 16 * 8 * 2;
        binconv_kernel<2, 2, true, true, 32, 32, 2><<<(wv + 3) / 4, 256, 0, stream>>>(
            a1, w2p, g2, b2, m2, v2, bias2, a2, N);
    }
    {   // conv3: XB=4 -> waves 256*16*4*4
        int wv = N * 16 * 4 * 4;
        binconv_kernel<2, 4, false, false, 16, 16, 4><<<(wv + 3) / 4, 256, 0, stream>>>(
            a2, w3p, g3, b3, m3, v3, nullptr, a3, N);
    }
    {   // conv4: pooled, XB=2 -> waves 256*8*4*4
        int wv = N * 8 * 4 * 4;
        binconv_kernel<4, 4, true, false, 16, 16, 2><<<(wv + 3) / 4, 256, 0, stream>>>(
            a3, w4p, g4, b4, m4, v4, nullptr, a4, N);
    }
    {   // conv5: XB=4 -> waves 256*8*2*8
        int wv = N * 8 * 2 * 8;
        binconv_kernel<4, 8, false, false, 8, 8, 4><<<(wv + 3) / 4, 256, 0, stream>>>(
            a4, w5p, g5, b5, m5, v5, nullptr, a5, N);
    }
    {   // conv6: pooled, XB=2 -> waves 256*4*2*8
        int wv = N * 4 * 2 * 8;
        binconv_kernel<8, 8, true, false, 8, 8, 2><<<(wv + 3) / 4, 256, 0, stream>>>(
            a5, w6p, g6, b6, m6, v6, nullptr, a6, N);
    }

    binfc_kernel<128, 16><<<(N * 16 + 3) / 4, 256, 0, stream>>>(a6, w7p, g7, b7, m7, v7, f7, N);
    binfc_kernel<16, 16><<<(N * 16 + 3) / 4, 256, 0, stream>>>(f7, w8p, g8, b8, m8, v8, f8, N);

    fc9_kernel<<<N, 64, 0, stream>>>(f8, w9p, m9, v9, (float*)d_out);
}

// Round 9
// 876.747 us; speedup vs baseline: 1.4271x; 1.4271x over previous
//
#include <hip/hip_runtime.h>
#include <stdint.h>

typedef unsigned long long u64;

static __device__ __forceinline__ int uread(int v) { return __builtin_amdgcn_readfirstlane(v); }
// force fp32 materialization (blocks fma-contraction / reassociation across steps)
static __device__ __forceinline__ float fr(float x) { __asm__ volatile("" : "+v"(x)); return x; }

// bn sign with numpy-faithful fp32 elementwise rounding (BIT-FROZEN since R7 pass):
static __device__ __forceinline__ bool bn_neg(float x, float g, float b, float m, float v) {
    float inv = fr(1.0f / fr(sqrtf(fr(v + 1e-5f))));
    float si  = fr(g * inv);
    float t1  = fr(x - m);
    float t2  = fr(t1 * si);
    float bn  = fr(t2 + b);
    return bn < 0.0f;
}

// ---------------- weight pack kernels (sign: x>=0 -> +1; bit=1 means -1) ----------------

__global__ __launch_bounds__(256) void packw1_kernel(const float* __restrict__ w, float* __restrict__ ws) {
    int id = blockIdx.x * 256 + threadIdx.x;
    if (id >= 27 * 128) return;
    int co = id & 127, j = id >> 7;
    ws[j * 128 + co] = (w[co * 27 + j] < 0.f) ? -1.f : 1.f;
}

// conv weights (COUT,CIN,3,3) -> bits [tap][word][COUT]; wave per (co,wrd), lane = channel-in-word.
// Coalesced-ish: lane reads 9 contiguous floats at base + lane*36B; ballot collects bit b = lane.
__global__ __launch_bounds__(256) void packw_conv2_kernel(const float* __restrict__ w, u64* __restrict__ wb,
                                                          int CINW, int COUT) {
    int wv = blockIdx.x * 4 + (threadIdx.x >> 6);
    if (wv >= COUT * CINW) return;
    int lane = threadIdx.x & 63;
    int wrd = wv % CINW, co = wv / CINW;
    int CIN = CINW * 64;
    const float* p = w + ((size_t)co * CIN + (size_t)wrd * 64 + lane) * 9;
    float f[9];
#pragma unroll
    for (int t = 0; t < 9; ++t) f[t] = p[t];
#pragma unroll
    for (int t = 0; t < 9; ++t) {
        u64 bits = __ballot(f[t] < 0.f);
        if (lane == 0) wb[(size_t)(t * CINW + wrd) * COUT + co] = bits;
    }
}

// w7 (1024,8192): wave per (o,cw); lane=c_local reads its 16 contiguous pixels (coalesced 4KB/wave)
__global__ __launch_bounds__(256) void packw7_kernel(const float* __restrict__ w, u64* __restrict__ wb) {
    int wv = blockIdx.x * 4 + (threadIdx.x >> 6);
    if (wv >= 1024 * 8) return;
    int lane = threadIdx.x & 63;
    int cw = wv & 7, o = wv >> 3;
    const float* p = w + (size_t)o * 8192 + (size_t)(cw * 64 + lane) * 16;
    float f[16];
#pragma unroll
    for (int i = 0; i < 16; i += 4) {
        float4 q = *(const float4*)(p + i);
        f[i] = q.x; f[i + 1] = q.y; f[i + 2] = q.z; f[i + 3] = q.w;
    }
#pragma unroll
    for (int pixel = 0; pixel < 16; ++pixel) {
        u64 bits = __ballot(f[pixel] < 0.f);
        if (lane == 0) wb[(size_t)(pixel * 8 + cw) * 1024 + o] = bits;
    }
}

// w8 (1024,1024) -> bits [k][1024]; wave per (o,k), lane = channel, coalesced 256B/wave.
__global__ __launch_bounds__(256) void packw8_kernel(const float* __restrict__ w, u64* __restrict__ wb) {
    int wv = blockIdx.x * 4 + (threadIdx.x >> 6);
    if (wv >= 1024 * 16) return;
    int lane = threadIdx.x & 63;
    int k = wv & 15, o = wv >> 4;
    float f = w[(size_t)o * 1024 + k * 64 + lane];
    u64 bits = __ballot(f < 0.f);
    if (lane == 0) wb[(size_t)k * 1024 + o] = bits;
}

// w9 (10,1024) -> bits [k][16] (slots o<10)
__global__ __launch_bounds__(256) void packw9_kernel(const float* __restrict__ w, u64* __restrict__ wb) {
    int wv = blockIdx.x * 4 + (threadIdx.x >> 6);
    if (wv >= 160) return;
    int lane = threadIdx.x & 63;
    int k = wv & 15, o = wv >> 4;
    float f = w[(size_t)o * 1024 + k * 64 + lane];
    u64 bits = __ballot(f < 0.f);
    if (lane == 0) wb[k * 16 + o] = bits;
}

// ---------------- conv1: fp32, Eigen/XLA-CPU accumulation order (BIT-FROZEN, R7 pass) ----------------
__global__ __launch_bounds__(256) void conv1_kernel(
    const float* __restrict__ x, const float* __restrict__ w1s,
    const float* __restrict__ g, const float* __restrict__ bb,
    const float* __restrict__ m, const float* __restrict__ v,
    u64* __restrict__ out, int N)
{
    int lane = threadIdx.x & 63;
    int rid = uread(blockIdx.x * 4 + (threadIdx.x >> 6));
    if (rid >= N * 32) return;
    int n = rid >> 5, y = rid & 31;
    const float* xb = x + (size_t)n * 3072;
    for (int half = 0; half < 2; ++half) {
        int co = half * 64 + lane;
        float w[27];
#pragma unroll
        for (int j = 0; j < 27; ++j) w[j] = w1s[j * 128 + co];
        float gc = g[co], bc = bb[co], mc = m[co], vc = v[co];
        for (int xx = 0; xx < 32; ++xx) {
            float acc = 0.f;
            // strict (ky, kx, ci) order — ci innermost — serial fmaf chain
            for (int ky = 0; ky < 3; ++ky) {
                int yy = y + ky - 1;
                if (yy < 0 || yy >= 32) continue;
                for (int kx = 0; kx < 3; ++kx) {
                    int xs = xx + kx - 1;
                    if (xs < 0 || xs >= 32) continue;
                    for (int ci = 0; ci < 3; ++ci)
                        acc = fmaf(w[ci * 9 + ky * 3 + kx], xb[ci * 1024 + yy * 32 + xs], acc);
                }
            }
            u64 bits = __ballot(bn_neg(acc, gc, bc, mc, vc));
            if (lane == 0) out[(((size_t)n * 32 + y) * 32 + xx) * 2 + half] = bits;
        }
    }
}

// ---------------- binary conv, LDS-staged (XNOR-popcount), fp32 bit-exact epilogue ----------------
// a: [n][H][W][WORDS] bits; wb: [tap*WORDS+w][COW*64]; out: [n][OH][OW][COW] bits
// Block = (n, y-chunk): stage activation slab in LDS once; waves read broadcast ds_read_b128
// with compile-time offsets; weights preloaded in VGPRs; pooled layers share a 4x4 patch
// across the 4 windows. All dots exact integers; epilogue frozen.
template<int WORDS, int COW, bool POOL, bool HAS_BIAS, int H, int YS>
__global__ __launch_bounds__(256) void binconv_lds(
    const u64* __restrict__ a, const u64* __restrict__ wb,
    const float* __restrict__ g, const float* __restrict__ bb,
    const float* __restrict__ m, const float* __restrict__ v,
    const float* __restrict__ bias, u64* __restrict__ out, int N)
{
    const int W = H;
    const int OH = POOL ? H / 2 : H, OW = POOL ? W / 2 : W;
    const int COUT = COW * 64;
    const int OROWS = OH / YS;
    const int RMAX = POOL ? OROWS * 2 + 2 : OROWS + 2;
    const int PR = POOL ? 4 : 3;          // patch rows/cols
    const int NW = POOL ? 4 : 1;          // windows per output
    const int W2 = WORDS / 2;             // ulonglong2 words per pixel

    __shared__ alignas(16) u64 tile[RMAX * W * WORDS];

    int blk = blockIdx.x;
    int ys = blk % YS, n = blk / YS;
    int oy0 = ys * OROWS;
    int iy0 = (POOL ? oy0 * 2 - 1 : oy0 - 1); if (iy0 < 0) iy0 = 0;
    int iy1 = (POOL ? (oy0 + OROWS - 1) * 2 + 2 : oy0 + OROWS); if (iy1 > H - 1) iy1 = H - 1;
    int R = iy1 - iy0 + 1;
    {
        const u64* src = a + ((size_t)(n * H + iy0) * W) * WORDS;
        int tot = R * W * WORDS;
        for (int i = threadIdx.x; i < tot; i += 256) tile[i] = src[i];
    }
    __syncthreads();

    int lane = threadIdx.x & 63;
    int wv = uread((int)(threadIdx.x >> 6));

    int cw0, r0, r1;
    if (COW >= 4) { cw0 = wv; r0 = 0; r1 = OROWS; }
    else { cw0 = wv % COW; int chunk = OROWS * COW / 4; r0 = (wv / COW) * chunk; r1 = r0 + chunk; }

    const ulonglong2* t2 = (const ulonglong2*)tile;

    for (int cw = cw0; cw < COW; cw += 4) {
        int co = cw * 64 + lane;
        u64 wgt[9 * WORDS];
#pragma unroll
        for (int t = 0; t < 9 * WORDS; ++t) wgt[t] = wb[(size_t)t * COUT + co];
        float gc = g[co], bc = bb[co], mc = m[co], vc = v[co];
        float bi = HAS_BIAS ? bias[co] : 0.f;

        for (int oy = oy0 + r0; oy < oy0 + r1; ++oy) {
            int y0 = (POOL ? oy * 2 : oy) - 1;            // patch global row 0
            bool rv[PR];
#pragma unroll
            for (int p = 0; p < PR; ++p) rv[p] = ((unsigned)(y0 + p) < (unsigned)H);
            for (int ox = 0; ox < OW; ++ox) {
                int x0 = (POOL ? ox * 2 : ox) - 1;        // patch global col 0
                bool cv[PR];
#pragma unroll
                for (int q = 0; q < PR; ++q) cv[q] = ((unsigned)(x0 + q) < (unsigned)W);

                int acc[NW], nb[NW];
#pragma unroll
                for (int i = 0; i < NW; ++i) { acc[i] = 0; nb[i] = 0; }
                // valid-tap counts (uniform scalar work)
#pragma unroll
                for (int sy = 0; sy < (POOL ? 2 : 1); ++sy)
#pragma unroll
                for (int sx = 0; sx < (POOL ? 2 : 1); ++sx)
#pragma unroll
                for (int ky = 0; ky < 3; ++ky)
#pragma unroll
                for (int kx = 0; kx < 3; ++kx)
                    if (rv[sy + ky] && cv[sx + kx]) nb[POOL ? sy * 2 + sx : 0] += WORDS * 64;

#pragma unroll
                for (int w2 = 0; w2 < W2; ++w2) {
                    ulonglong2 pt[PR][PR];
#pragma unroll
                    for (int p = 0; p < PR; ++p) if (rv[p]) {
                        int lrow = y0 + p - iy0;
#pragma unroll
                        for (int q = 0; q < PR; ++q) if (cv[q])
                            pt[p][q] = t2[(lrow * W + (x0 + q)) * W2 + w2];
                    }
#pragma unroll
                    for (int sy = 0; sy < (POOL ? 2 : 1); ++sy)
#pragma unroll
                    for (int sx = 0; sx < (POOL ? 2 : 1); ++sx)
#pragma unroll
                    for (int ky = 0; ky < 3; ++ky)
#pragma unroll
                    for (int kx = 0; kx < 3; ++kx)
                        if (rv[sy + ky] && cv[sx + kx]) {
                            ulonglong2 q = pt[sy + ky][sx + kx];
                            int wi = POOL ? sy * 2 + sx : 0;
                            acc[wi] += __popcll(q.x ^ wgt[(ky * 3 + kx) * WORDS + 2 * w2])
                                     + __popcll(q.y ^ wgt[(ky * 3 + kx) * WORDS + 2 * w2 + 1]);
                        }
                }
                int best = 0;
#pragma unroll
                for (int i = 0; i < NW; ++i) {
                    int dot = nb[i] - 2 * acc[i];          // exact integer
                    best = (i == 0) ? dot : max(best, dot);
                }
                // fl monotone => max commutes with (dot+bias) rounding; epilogue frozen.
                float tv = (float)best;
                if (HAS_BIAS) tv = fr(tv + bi);
                u64 bits = __ballot(bn_neg(tv, gc, bc, mc, vc));
                if (lane == 0) out[((size_t)(n * OH + oy) * OW + ox) * COW + cw] = bits;
            }
        }
    }
}

// ---------------- binary FC, fp32 bit-exact epilogue (frozen) ----------------
template<int KW, int OWRD>
__global__ __launch_bounds__(256) void binfc_kernel(
    const u64* __restrict__ a, const u64* __restrict__ wb,
    const float* __restrict__ g, const float* __restrict__ bb,
    const float* __restrict__ m, const float* __restrict__ v,
    u64* __restrict__ out, int N)
{
    int lane = threadIdx.x & 63;
    int wid = uread(blockIdx.x * 4 + (threadIdx.x >> 6));
    if (wid >= N * OWRD) return;
    int ow = wid & (OWRD - 1), n = wid / OWRD;
    int o = ow * 64 + lane;
    const u64* ap = a + (size_t)n * KW;
    int acc = 0;
#pragma unroll 8
    for (int k = 0; k < KW; ++k)
        acc += __popcll(ap[k] ^ wb[(size_t)k * (OWRD * 64) + o]);
    float dotf = (float)(KW * 64 - 2 * acc);
    u64 bits = __ballot(bn_neg(dotf, g[o], bb[o], m[o], v[o]));
    if (lane == 0) out[(size_t)n * OWRD + ow] = bits;
}

// ---------------- fc9 + bn(affine=False) + log_softmax, fp32 output (frozen) ----------------
__global__ __launch_bounds__(64) void fc9_kernel(
    const u64* __restrict__ a, const u64* __restrict__ wb,
    const float* __restrict__ m, const float* __restrict__ v, float* __restrict__ out)
{
    int n = blockIdx.x, t = threadIdx.x;
    const u64* ap = a + (size_t)n * 16;
    float val = -1e30f;
    if (t < 10) {
        int acc = 0;
#pragma unroll
        for (int k = 0; k < 16; ++k) acc += __popcll(ap[k] ^ wb[k * 16 + t]);
        float dotf = (float)(1024 - 2 * acc);
        float inv = fr(1.0f / fr(sqrtf(fr(v[t] + 1e-5f))));
        float t1  = fr(dotf - m[t]);
        val = fr(t1 * inv);
    }
    float mx = val;
#pragma unroll
    for (int off = 32; off; off >>= 1) mx = fmaxf(mx, __shfl_xor(mx, off));
    float sh = fr(val - mx);
    double e = (t < 10) ? exp((double)sh) : 0.0;
    double sum = e;
#pragma unroll
    for (int off = 32; off; off >>= 1) sum += __shfl_xor(sum, off);
    if (t < 10) out[n * 10 + t] = (float)((double)sh - log(sum));
}

extern "C" void kernel_launch(void* const* d_in, const int* in_sizes, int n_in,
                              void* d_out, int out_size, void* d_ws, size_t ws_size,
                              hipStream_t stream) {
    // setup_inputs() dict order
    auto F = [&](int i) { return (const float*)d_in[i]; };
    const float* x  = F(0);
    const float* w1 = F(1);  const float* g1 = F(2);  const float* b1 = F(3);
    const float* m1 = F(4);  const float* v1 = F(5);
    const float* w2 = F(6);  const float* g2 = F(7);  const float* b2 = F(8);
    const float* m2 = F(9);  const float* v2 = F(10);
    const float* w3 = F(11); const float* g3 = F(12); const float* b3 = F(13);
    const float* m3 = F(14); const float* v3 = F(15);
    const float* w4 = F(16); const float* g4 = F(17); const float* b4 = F(18);
    const float* m4 = F(19); const float* v4 = F(20);
    const float* w5 = F(21); const float* g5 = F(22); const float* b5 = F(23);
    const float* m5 = F(24); const float* v5 = F(25);
    const float* w6 = F(26); const float* g6 = F(27); const float* b6 = F(28);
    const float* m6 = F(29); const float* v6 = F(30);
    const float* bias2 = F(31);
    const float* w7 = F(32); const float* m7 = F(33); const float* v7 = F(34);
    const float* g7 = F(35); const float* b7 = F(36);
    const float* w8 = F(37); const float* m8 = F(38); const float* v8 = F(39);
    const float* g8 = F(40); const float* b8 = F(41);
    const float* w9 = F(42); const float* m9 = F(43); const float* v9 = F(44);
    (void)in_sizes; (void)n_in; (void)ws_size;

    const int N = out_size / 10;
    u64* ws = (u64*)d_ws;
    size_t off = 0;
    auto carve = [&](size_t nwords) { u64* p = ws + off; off += nwords; return p; };
    float* w1s = (float*)carve(1728);
    u64* w2p = carve(2304);
    u64* w3p = carve(4608);
    u64* w4p = carve(9216);
    u64* w5p = carve(18432);
    u64* w6p = carve(36864);
    u64* w7p = carve(131072);
    u64* w8p = carve(16384);
    u64* w9p = carve(256);
    u64* a1 = carve((size_t)N * 32 * 32 * 2);
    u64* a2 = carve((size_t)N * 16 * 16 * 2);
    u64* a3 = carve((size_t)N * 16 * 16 * 4);
    u64* a4 = carve((size_t)N * 8 * 8 * 4);
    u64* a5 = carve((size_t)N * 8 * 8 * 8);
    u64* a6 = carve((size_t)N * 16 * 8);
    u64* f7 = carve((size_t)N * 16);
    u64* f8 = carve((size_t)N * 16);

    packw1_kernel<<<(3456 + 255) / 256, 256, 0, stream>>>(w1, w1s);
    packw_conv2_kernel<<<(128 * 2 + 3) / 4, 256, 0, stream>>>(w2, w2p, 2, 128);
    packw_conv2_kernel<<<(256 * 2 + 3) / 4, 256, 0, stream>>>(w3, w3p, 2, 256);
    packw_conv2_kernel<<<(256 * 4 + 3) / 4, 256, 0, stream>>>(w4, w4p, 4, 256);
    packw_conv2_kernel<<<(512 * 4 + 3) / 4, 256, 0, stream>>>(w5, w5p, 4, 512);
    packw_conv2_kernel<<<(512 * 8 + 3) / 4, 256, 0, stream>>>(w6, w6p, 8, 512);
    packw7_kernel<<<(8192 + 3) / 4, 256, 0, stream>>>(w7, w7p);
    packw8_kernel<<<(16384 + 3) / 4, 256, 0, stream>>>(w8, w8p);
    packw9_kernel<<<(160 + 3) / 4, 256, 0, stream>>>(w9, w9p);

    conv1_kernel<<<(N * 32 + 3) / 4, 256, 0, stream>>>(x, w1s, g1, b1, m1, v1, a1, N);

    // binconv: block = (n, y-half), 512 blocks x 256 threads
    binconv_lds<2, 2, true, true, 32, 2><<<N * 2, 256, 0, stream>>>(
        a1, w2p, g2, b2, m2, v2, bias2, a2, N);
    binconv_lds<2, 4, false, false, 16, 2><<<N * 2, 256, 0, stream>>>(
        a2, w3p, g3, b3, m3, v3, nullptr, a3, N);
    binconv_lds<4, 4, true, false, 16, 2><<<N * 2, 256, 0, stream>>>(
        a3, w4p, g4, b4, m4, v4, nullptr, a4, N);
    binconv_lds<4, 8, false, false, 8, 2><<<N * 2, 256, 0, stream>>>(
        a4, w5p, g5, b5, m5, v5, nullptr, a5, N);
    binconv_lds<8, 8, true, false, 8, 2><<<N * 2, 256, 0, stream>>>(
        a5, w6p, g6, b6, m6, v6, nullptr, a6, N);

    binfc_kernel<128, 16><<<(N * 16 + 3) / 4, 256, 0, stream>>>(a6, w7p, g7, b7, m7, v7, f7, N);
    binfc_kernel<16, 16><<<(N * 16 + 3) / 4, 256, 0, stream>>>(f7, w8p, g8, b8, m8, v8, f8, N);

    fc9_kernel<<<N, 64, 0, stream>>>(f8, w9p, m9, v9, (float*)d_out);
}

// Round 10
// 813.418 us; speedup vs baseline: 1.5382x; 1.0779x over previous
//
#include <hip/hip_runtime.h>
#include <stdint.h>

typedef unsigned long long u64;

static __device__ __forceinline__ int uread(int v) { return __builtin_amdgcn_readfirstlane(v); }
// force fp32 materialization (blocks fma-contraction / reassociation / load-sinking)
static __device__ __forceinline__ float fr(float x) { __asm__ volatile("" : "+v"(x)); return x; }

// bn sign with numpy-faithful fp32 elementwise rounding (BIT-FROZEN since R7 pass):
static __device__ __forceinline__ bool bn_neg(float x, float g, float b, float m, float v) {
    float inv = fr(1.0f / fr(sqrtf(fr(v + 1e-5f))));
    float si  = fr(g * inv);
    float t1  = fr(x - m);
    float t2  = fr(t1 * si);
    float bn  = fr(t2 + b);
    return bn < 0.0f;
}

// ---------------- weight pack kernels (sign: x>=0 -> +1; bit=1 means -1) ----------------

__global__ __launch_bounds__(256) void packw1_kernel(const float* __restrict__ w, float* __restrict__ ws) {
    int id = blockIdx.x * 256 + threadIdx.x;
    if (id >= 27 * 128) return;
    int co = id & 127, j = id >> 7;
    ws[j * 128 + co] = (w[co * 27 + j] < 0.f) ? -1.f : 1.f;
}

// conv weights (COUT,CIN,3,3) -> bits [tap][word][COUT]; wave per (co,wrd), lane = channel-in-word.
__global__ __launch_bounds__(256) void packw_conv2_kernel(const float* __restrict__ w, u64* __restrict__ wb,
                                                          int CINW, int COUT) {
    int wv = blockIdx.x * 4 + (threadIdx.x >> 6);
    if (wv >= COUT * CINW) return;
    int lane = threadIdx.x & 63;
    int wrd = wv % CINW, co = wv / CINW;
    int CIN = CINW * 64;
    const float* p = w + ((size_t)co * CIN + (size_t)wrd * 64 + lane) * 9;
    float f[9];
#pragma unroll
    for (int t = 0; t < 9; ++t) f[t] = p[t];
#pragma unroll
    for (int t = 0; t < 9; ++t) {
        u64 bits = __ballot(f[t] < 0.f);
        if (lane == 0) wb[(size_t)(t * CINW + wrd) * COUT + co] = bits;
    }
}

// w7 (1024,8192): wave per (o,cw); lane=c_local reads its 16 contiguous pixels (coalesced 4KB/wave)
__global__ __launch_bounds__(256) void packw7_kernel(const float* __restrict__ w, u64* __restrict__ wb) {
    int wv = blockIdx.x * 4 + (threadIdx.x >> 6);
    if (wv >= 1024 * 8) return;
    int lane = threadIdx.x & 63;
    int cw = wv & 7, o = wv >> 3;
    const float* p = w + (size_t)o * 8192 + (size_t)(cw * 64 + lane) * 16;
    float f[16];
#pragma unroll
    for (int i = 0; i < 16; i += 4) {
        float4 q = *(const float4*)(p + i);
        f[i] = q.x; f[i + 1] = q.y; f[i + 2] = q.z; f[i + 3] = q.w;
    }
#pragma unroll
    for (int pixel = 0; pixel < 16; ++pixel) {
        u64 bits = __ballot(f[pixel] < 0.f);
        if (lane == 0) wb[(size_t)(pixel * 8 + cw) * 1024 + o] = bits;
    }
}

// w8 (1024,1024) -> bits [k][1024]; wave per (o,k), lane = channel, coalesced 256B/wave.
__global__ __launch_bounds__(256) void packw8_kernel(const float* __restrict__ w, u64* __restrict__ wb) {
    int wv = blockIdx.x * 4 + (threadIdx.x >> 6);
    if (wv >= 1024 * 16) return;
    int lane = threadIdx.x & 63;
    int k = wv & 15, o = wv >> 4;
    float f = w[(size_t)o * 1024 + k * 64 + lane];
    u64 bits = __ballot(f < 0.f);
    if (lane == 0) wb[(size_t)k * 1024 + o] = bits;
}

// w9 (10,1024) -> bits [k][16] (slots o<10)
__global__ __launch_bounds__(256) void packw9_kernel(const float* __restrict__ w, u64* __restrict__ wb) {
    int wv = blockIdx.x * 4 + (threadIdx.x >> 6);
    if (wv >= 160) return;
    int lane = threadIdx.x & 63;
    int k = wv & 15, o = wv >> 4;
    float f = w[(size_t)o * 1024 + k * 64 + lane];
    u64 bits = __ballot(f < 0.f);
    if (lane == 0) wb[k * 16 + o] = bits;
}

// ---------------- conv1: fp32, Eigen/XLA-CPU order (BIT-FROZEN chain), register-resident ----------------
// Sliding 3-column window (9 new uniform x-loads per output), both co-halves fused (2 indep
// FMA chains), weights pinned in VGPRs via fr(). OOB taps = fmaf(w,0,acc) exact no-ops
// (zero-sign differences are epilogue-invisible). Chain order (ky, kx, ci) preserved exactly.
__global__ __launch_bounds__(256, 4) void conv1_kernel(
    const float* __restrict__ x, const float* __restrict__ w1s,
    const float* __restrict__ g, const float* __restrict__ bb,
    const float* __restrict__ m, const float* __restrict__ v,
    u64* __restrict__ out, int N)
{
    int lane = threadIdx.x & 63;
    int rid = uread(blockIdx.x * 4 + (threadIdx.x >> 6));
    if (rid >= N * 32) return;
    int n = rid >> 5, y = rid & 31;
    const float* xb = x + (size_t)n * 3072;
    const bool rv0 = (y > 0), rv2 = (y < 31);
    const int y0 = rv0 ? y - 1 : 0, y2 = rv2 ? y + 1 : 31;

    int co0 = lane, co1 = 64 + lane;
    float w0[27], w1[27];
#pragma unroll
    for (int j = 0; j < 27; ++j) {
        w0[j] = fr(w1s[j * 128 + co0]);
        w1[j] = fr(w1s[j * 128 + co1]);
    }
    float g0 = g[co0], b0 = bb[co0], m0 = m[co0], v0 = v[co0];
    float g1 = g[co1], b1 = bb[co1], m1 = m[co1], v1 = v[co1];

    // columns: c[ky*3+ci], wave-uniform values
    float cm[9], cc[9], cn[9];
#pragma unroll
    for (int t = 0; t < 9; ++t) cm[t] = 0.f;

    auto ldcol = [&](float* c, int xs) {
#pragma unroll
        for (int ci = 0; ci < 3; ++ci) {
            float a0 = xb[ci * 1024 + y0 * 32 + xs];
            float a1 = xb[ci * 1024 + y  * 32 + xs];
            float a2 = xb[ci * 1024 + y2 * 32 + xs];
            c[0 + ci] = fr(rv0 ? a0 : 0.f);
            c[3 + ci] = fr(a1);
            c[6 + ci] = fr(rv2 ? a2 : 0.f);
        }
    };
    ldcol(cc, 0);

    u64* orow = out + (((size_t)n * 32 + y) * 32) * 2;

    for (int xx = 0; xx < 32; ++xx) {
        if (xx < 31) ldcol(cn, xx + 1);
        else {
#pragma unroll
            for (int t = 0; t < 9; ++t) cn[t] = 0.f;
        }
        float a0 = 0.f, a1 = 0.f;
#pragma unroll
        for (int ky = 0; ky < 3; ++ky) {
#pragma unroll
            for (int ci = 0; ci < 3; ++ci) a0 = fmaf(w0[ci * 9 + ky * 3 + 0], cm[ky * 3 + ci], a0);
#pragma unroll
            for (int ci = 0; ci < 3; ++ci) a0 = fmaf(w0[ci * 9 + ky * 3 + 1], cc[ky * 3 + ci], a0);
#pragma unroll
            for (int ci = 0; ci < 3; ++ci) a0 = fmaf(w0[ci * 9 + ky * 3 + 2], cn[ky * 3 + ci], a0);
        }
#pragma unroll
        for (int ky = 0; ky < 3; ++ky) {
#pragma unroll
            for (int ci = 0; ci < 3; ++ci) a1 = fmaf(w1[ci * 9 + ky * 3 + 0], cm[ky * 3 + ci], a1);
#pragma unroll
            for (int ci = 0; ci < 3; ++ci) a1 = fmaf(w1[ci * 9 + ky * 3 + 1], cc[ky * 3 + ci], a1);
#pragma unroll
            for (int ci = 0; ci < 3; ++ci) a1 = fmaf(w1[ci * 9 + ky * 3 + 2], cn[ky * 3 + ci], a1);
        }
        u64 bits0 = __ballot(bn_neg(a0, g0, b0, m0, v0));
        u64 bits1 = __ballot(bn_neg(a1, g1, b1, m1, v1));
        if (lane == 0) {
            ulonglong2 st; st.x = bits0; st.y = bits1;
            *(ulonglong2*)(orow + xx * 2) = st;
        }
#pragma unroll
        for (int t = 0; t < 9; ++t) { cm[t] = cc[t]; cc[t] = cn[t]; }
    }
}

// ---------------- binary conv, LDS-staged (XNOR-popcount), fp32 bit-exact epilogue ----------------
template<int WORDS, int COW, bool POOL, bool HAS_BIAS, int H, int YS>
__global__ __launch_bounds__(256) void binconv_lds(
    const u64* __restrict__ a, const u64* __restrict__ wb,
    const float* __restrict__ g, const float* __restrict__ bb,
    const float* __restrict__ m, const float* __restrict__ v,
    const float* __restrict__ bias, u64* __restrict__ out, int N)
{
    const int W = H;
    const int OH = POOL ? H / 2 : H, OW = POOL ? W / 2 : W;
    const int COUT = COW * 64;
    const int OROWS = OH / YS;
    const int RMAX = POOL ? OROWS * 2 + 2 : OROWS + 2;
    const int PR = POOL ? 4 : 3;
    const int NW = POOL ? 4 : 1;
    const int W2 = WORDS / 2;

    __shared__ alignas(16) u64 tile[RMAX * W * WORDS];

    int blk = blockIdx.x;
    int ys = blk % YS, n = blk / YS;
    int oy0 = ys * OROWS;
    int iy0 = (POOL ? oy0 * 2 - 1 : oy0 - 1); if (iy0 < 0) iy0 = 0;
    int iy1 = (POOL ? (oy0 + OROWS - 1) * 2 + 2 : oy0 + OROWS); if (iy1 > H - 1) iy1 = H - 1;
    int R = iy1 - iy0 + 1;
    {
        const u64* src = a + ((size_t)(n * H + iy0) * W) * WORDS;
        int tot = R * W * WORDS;
        for (int i = threadIdx.x; i < tot; i += 256) tile[i] = src[i];
    }
    __syncthreads();

    int lane = threadIdx.x & 63;
    int wv = uread((int)(threadIdx.x >> 6));

    int cw0, r0, r1;
    if (COW >= 4) { cw0 = wv; r0 = 0; r1 = OROWS; }
    else { cw0 = wv % COW; int chunk = OROWS * COW / 4; r0 = (wv / COW) * chunk; r1 = r0 + chunk; }

    const ulonglong2* t2 = (const ulonglong2*)tile;

    for (int cw = cw0; cw < COW; cw += 4) {
        int co = cw * 64 + lane;
        u64 wgt[9 * WORDS];
#pragma unroll
        for (int t = 0; t < 9 * WORDS; ++t) wgt[t] = wb[(size_t)t * COUT + co];
        float gc = g[co], bc = bb[co], mc = m[co], vc = v[co];
        float bi = HAS_BIAS ? bias[co] : 0.f;

        for (int oy = oy0 + r0; oy < oy0 + r1; ++oy) {
            int y0 = (POOL ? oy * 2 : oy) - 1;
            bool rv[PR];
#pragma unroll
            for (int p = 0; p < PR; ++p) rv[p] = ((unsigned)(y0 + p) < (unsigned)H);
            for (int ox = 0; ox < OW; ++ox) {
                int x0 = (POOL ? ox * 2 : ox) - 1;
                bool cv[PR];
#pragma unroll
                for (int q = 0; q < PR; ++q) cv[q] = ((unsigned)(x0 + q) < (unsigned)W);

                int acc[NW], nb[NW];
#pragma unroll
                for (int i = 0; i < NW; ++i) { acc[i] = 0; nb[i] = 0; }
#pragma unroll
                for (int sy = 0; sy < (POOL ? 2 : 1); ++sy)
#pragma unroll
                for (int sx = 0; sx < (POOL ? 2 : 1); ++sx)
#pragma unroll
                for (int ky = 0; ky < 3; ++ky)
#pragma unroll
                for (int kx = 0; kx < 3; ++kx)
                    if (rv[sy + ky] && cv[sx + kx]) nb[POOL ? sy * 2 + sx : 0] += WORDS * 64;

#pragma unroll
                for (int w2 = 0; w2 < W2; ++w2) {
                    ulonglong2 pt[PR][PR];
#pragma unroll
                    for (int p = 0; p < PR; ++p) if (rv[p]) {
                        int lrow = y0 + p - iy0;
#pragma unroll
                        for (int q = 0; q < PR; ++q) if (cv[q])
                            pt[p][q] = t2[(lrow * W + (x0 + q)) * W2 + w2];
                    }
#pragma unroll
                    for (int sy = 0; sy < (POOL ? 2 : 1); ++sy)
#pragma unroll
                    for (int sx = 0; sx < (POOL ? 2 : 1); ++sx)
#pragma unroll
                    for (int ky = 0; ky < 3; ++ky)
#pragma unroll
                    for (int kx = 0; kx < 3; ++kx)
                        if (rv[sy + ky] && cv[sx + kx]) {
                            ulonglong2 q = pt[sy + ky][sx + kx];
                            int wi = POOL ? sy * 2 + sx : 0;
                            acc[wi] += __popcll(q.x ^ wgt[(ky * 3 + kx) * WORDS + 2 * w2])
                                     + __popcll(q.y ^ wgt[(ky * 3 + kx) * WORDS + 2 * w2 + 1]);
                        }
                }
                int best = 0;
#pragma unroll
                for (int i = 0; i < NW; ++i) {
                    int dot = nb[i] - 2 * acc[i];
                    best = (i == 0) ? dot : max(best, dot);
                }
                float tv = (float)best;
                if (HAS_BIAS) tv = fr(tv + bi);
                u64 bits = __ballot(bn_neg(tv, gc, bc, mc, vc));
                if (lane == 0) out[((size_t)(n * OH + oy) * OW + ox) * COW + cw] = bits;
            }
        }
    }
}

// ---------------- binary FC, fp32 bit-exact epilogue (frozen) ----------------
template<int KW, int OWRD>
__global__ __launch_bounds__(256) void binfc_kernel(
    const u64* __restrict__ a, const u64* __restrict__ wb,
    const float* __restrict__ g, const float* __restrict__ bb,
    const float* __restrict__ m, const float* __restrict__ v,
    u64* __restrict__ out, int N)
{
    int lane = threadIdx.x & 63;
    int wid = uread(blockIdx.x * 4 + (threadIdx.x >> 6));
    if (wid >= N * OWRD) return;
    int ow = wid & (OWRD - 1), n = wid / OWRD;
    int o = ow * 64 + lane;
    const u64* ap = a + (size_t)n * KW;
    int acc = 0;
#pragma unroll 8
    for (int k = 0; k < KW; ++k)
        acc += __popcll(ap[k] ^ wb[(size_t)k * (OWRD * 64) + o]);
    float dotf = (float)(KW * 64 - 2 * acc);
    u64 bits = __ballot(bn_neg(dotf, g[o], bb[o], m[o], v[o]));
    if (lane == 0) out[(size_t)n * OWRD + ow] = bits;
}

// ---------------- fc9 + bn(affine=False) + log_softmax, fp32 output (frozen) ----------------
__global__ __launch_bounds__(64) void fc9_kernel(
    const u64* __restrict__ a, const u64* __restrict__ wb,
    const float* __restrict__ m, const float* __restrict__ v, float* __restrict__ out)
{
    int n = blockIdx.x, t = threadIdx.x;
    const u64* ap = a + (size_t)n * 16;
    float val = -1e30f;
    if (t < 10) {
        int acc = 0;
#pragma unroll
        for (int k = 0; k < 16; ++k) acc += __popcll(ap[k] ^ wb[k * 16 + t]);
        float dotf = (float)(1024 - 2 * acc);
        float inv = fr(1.0f / fr(sqrtf(fr(v[t] + 1e-5f))));
        float t1  = fr(dotf - m[t]);
        val = fr(t1 * inv);
    }
    float mx = val;
#pragma unroll
    for (int off = 32; off; off >>= 1) mx = fmaxf(mx, __shfl_xor(mx, off));
    float sh = fr(val - mx);
    double e = (t < 10) ? exp((double)sh) : 0.0;
    double sum = e;
#pragma unroll
    for (int off = 32; off; off >>= 1) sum += __shfl_xor(sum, off);
    if (t < 10) out[n * 10 + t] = (float)((double)sh - log(sum));
}

extern "C" void kernel_launch(void* const* d_in, const int* in_sizes, int n_in,
                              void* d_out, int out_size, void* d_ws, size_t ws_size,
                              hipStream_t stream) {
    // setup_inputs() dict order
    auto F = [&](int i) { return (const float*)d_in[i]; };
    const float* x  = F(0);
    const float* w1 = F(1);  const float* g1 = F(2);  const float* b1 = F(3);
    const float* m1 = F(4);  const float* v1 = F(5);
    const float* w2 = F(6);  const float* g2 = F(7);  const float* b2 = F(8);
    const float* m2 = F(9);  const float* v2 = F(10);
    const float* w3 = F(11); const float* g3 = F(12); const float* b3 = F(13);
    const float* m3 = F(14); const float* v3 = F(15);
    const float* w4 = F(16); const float* g4 = F(17); const float* b4 = F(18);
    const float* m4 = F(19); const float* v4 = F(20);
    const float* w5 = F(21); const float* g5 = F(22); const float* b5 = F(23);
    const float* m5 = F(24); const float* v5 = F(25);
    const float* w6 = F(26); const float* g6 = F(27); const float* b6 = F(28);
    const float* m6 = F(29); const float* v6 = F(30);
    const float* bias2 = F(31);
    const float* w7 = F(32); const float* m7 = F(33); const float* v7 = F(34);
    const float* g7 = F(35); const float* b7 = F(36);
    const float* w8 = F(37); const float* m8 = F(38); const float* v8 = F(39);
    const float* g8 = F(40); const float* b8 = F(41);
    const float* w9 = F(42); const float* m9 = F(43); const float* v9 = F(44);
    (void)in_sizes; (void)n_in; (void)ws_size;

    const int N = out_size / 10;
    u64* ws = (u64*)d_ws;
    size_t off = 0;
    auto carve = [&](size_t nwords) { u64* p = ws + off; off += nwords; return p; };
    float* w1s = (float*)carve(1728);
    u64* w2p = carve(2304);
    u64* w3p = carve(4608);
    u64* w4p = carve(9216);
    u64* w5p = carve(18432);
    u64* w6p = carve(36864);
    u64* w7p = carve(131072);
    u64* w8p = carve(16384);
    u64* w9p = carve(256);
    u64* a1 = carve((size_t)N * 32 * 32 * 2);
    u64* a2 = carve((size_t)N * 16 * 16 * 2);
    u64* a3 = carve((size_t)N * 16 * 16 * 4);
    u64* a4 = carve((size_t)N * 8 * 8 * 4);
    u64* a5 = carve((size_t)N * 8 * 8 * 8);
    u64* a6 = carve((size_t)N * 16 * 8);
    u64* f7 = carve((size_t)N * 16);
    u64* f8 = carve((size_t)N * 16);

    packw1_kernel<<<(3456 + 255) / 256, 256, 0, stream>>>(w1, w1s);
    packw_conv2_kernel<<<(128 * 2 + 3) / 4, 256, 0, stream>>>(w2, w2p, 2, 128);
    packw_conv2_kernel<<<(256 * 2 + 3) / 4, 256, 0, stream>>>(w3, w3p, 2, 256);
    packw_conv2_kernel<<<(256 * 4 + 3) / 4, 256, 0, stream>>>(w4, w4p, 4, 256);
    packw_conv2_kernel<<<(512 * 4 + 3) / 4, 256, 0, stream>>>(w5, w5p, 4, 512);
    packw_conv2_kernel<<<(512 * 8 + 3) / 4, 256, 0, stream>>>(w6, w6p, 8, 512);
    packw7_kernel<<<(8192 + 3) / 4, 256, 0, stream>>>(w7, w7p);
    packw8_kernel<<<(16384 + 3) / 4, 256, 0, stream>>>(w8, w8p);
    packw9_kernel<<<(160 + 3) / 4, 256, 0, stream>>>(w9, w9p);

    conv1_kernel<<<(N * 32 + 3) / 4, 256, 0, stream>>>(x, w1s, g1, b1, m1, v1, a1, N);

    // binconv: block = (n, y-half), 512 blocks x 256 threads
    binconv_lds<2, 2, true, true, 32, 2><<<N * 2, 256, 0, stream>>>(
        a1, w2p, g2, b2, m2, v2, bias2, a2, N);
    binconv_lds<2, 4, false, false, 16, 2><<<N * 2, 256, 0, stream>>>(
        a2, w3p, g3, b3, m3, v3, nullptr, a3, N);
    binconv_lds<4, 4, true, false, 16, 2><<<N * 2, 256, 0, stream>>>(
        a3, w4p, g4, b4, m4, v4, nullptr, a4, N);
    binconv_lds<4, 8, false, false, 8, 2><<<N * 2, 256, 0, stream>>>(
        a4, w5p, g5, b5, m5, v5, nullptr, a5, N);
    binconv_lds<8, 8, true, false, 8, 2><<<N * 2, 256, 0, stream>>>(
        a5, w6p, g6, b6, m6, v6, nullptr, a6, N);

    binfc_kernel<128, 16><<<(N * 16 + 3) / 4, 256, 0, stream>>>(a6, w7p, g7, b7, m7, v7, f7, N);
    binfc_kernel<16, 16><<<(N * 16 + 3) / 4, 256, 0, stream>>>(f7, w8p, g8, b8, m8, v8, f8, N);

    fc9_kernel<<<N, 64, 0, stream>>>(f8, w9p, m9, v9, (float*)d_out);
}